// Round 1
// baseline (4155.217 us; speedup 1.0000x reference)
//
#include <hip/hip_runtime.h>

// Problem constants (fixed by reference).
constexpr int NNODES = 200000;
constexpr int NAUT   = 100000;
constexpr int NEDGE  = 600000;
constexpr int HIDC   = 128;
constexpr int OUTCH  = 64;
constexpr int RELS   = 4;

// ---------------- prep kernels ----------------

// W[r][i][o] = sum_b comp[r][b] * basis[b][i][o]
__global__ void makew_kernel(const float* __restrict__ basis, const float* __restrict__ comp,
                             float* __restrict__ W, int io_sz) {
    int idx = blockIdx.x * 256 + threadIdx.x;
    if (idx >= RELS * io_sz) return;
    int r = idx / io_sz, io = idx % io_sz;
    float s = 0.f;
#pragma unroll
    for (int b = 0; b < 4; b++) s += comp[r * 4 + b] * basis[b * io_sz + io];
    W[idx] = s;
}

__global__ void count_kernel(const int* __restrict__ dst, const int* __restrict__ et,
                             float* __restrict__ cnt) {
    int e = blockIdx.x * 256 + threadIdx.x;
    if (e < NEDGE) atomicAdd(&cnt[et[e] * NNODES + dst[e]], 1.0f);
}

__global__ void relcount_kernel(const float* __restrict__ cnt, int* __restrict__ relcnt) {
    __shared__ float red[256];
    int r = blockIdx.x;
    float s = 0.f;
    for (int i = threadIdx.x; i < NNODES; i += 256) s += cnt[r * NNODES + i];
    red[threadIdx.x] = s;
    __syncthreads();
    for (int st = 128; st > 0; st >>= 1) {
        if (threadIdx.x < st) red[threadIdx.x] += red[threadIdx.x + st];
        __syncthreads();
    }
    if (threadIdx.x == 0) relcnt[r] = (int)(red[0] + 0.5f);
}

__global__ void prefix_kernel(const int* __restrict__ relcnt, int* __restrict__ eoff,
                              int* __restrict__ cursor) {
    if (threadIdx.x == 0 && blockIdx.x == 0) {
        int acc = 0;
        for (int r = 0; r < RELS; r++) { eoff[r] = acc; cursor[r] = 0; acc += relcnt[r]; }
        eoff[RELS] = acc;
    }
}

__global__ void inv_kernel(float* __restrict__ cnt) {
    int i = blockIdx.x * 256 + threadIdx.x;
    if (i < RELS * NNODES) cnt[i] = 1.0f / fmaxf(cnt[i], 1.0f);
}

// Compact edge ids per relation; wave-aggregated atomics (4 atomics/wave, not 64).
__global__ void build_kernel(const int* __restrict__ et, const int* __restrict__ eoff,
                             int* __restrict__ cursor, int* __restrict__ elist) {
    int e = blockIdx.x * 256 + threadIdx.x;
    bool valid = e < NEDGE;
    int r = valid ? et[e] : -1;
    int lane = threadIdx.x & 63;
    for (int rr = 0; rr < RELS; rr++) {
        unsigned long long mask = __ballot(valid && (r == rr));
        if (mask == 0ull) continue;
        int leader = __builtin_ctzll(mask);
        int total = __builtin_popcountll(mask);
        int base = 0;
        if (lane == leader) base = atomicAdd(&cursor[rr], total);
        base = __shfl(base, leader, 64);
        if (valid && r == rr) {
            int pre = __builtin_popcountll(mask & ((1ull << lane) - 1ull));
            elist[eoff[rr] + base + pre] = e;
        }
    }
}

__global__ void relu_kernel(float* __restrict__ p, int n) {
    int i = blockIdx.x * 256 + threadIdx.x;
    if (i < n) p[i] = fmaxf(p[i], 0.f);
}

// ---------------- GEMM: C[M,NC] = act(A[M,K] @ B[K,NC] + bias) ----------------
// 256 threads, tile 64 rows x NC cols, 8 rows x (NC/32) cols per thread.
template <int NC>
__global__ __launch_bounds__(256) void gemm_kernel(const float* __restrict__ A,
                                                   const float* __restrict__ B,
                                                   const float* __restrict__ bias,
                                                   float* __restrict__ C, int M, int K,
                                                   int relu) {
    constexpr int NCT = NC / 32;
    __shared__ float sB[128 * NC];
    __shared__ float sA[64 * 128];
    int tid = threadIdx.x;
    int row0 = blockIdx.x * 64;

    for (int i = tid; i < (K * NC) >> 2; i += 256)
        ((float4*)sB)[i] = ((const float4*)B)[i];
    for (int i = tid; i < (64 * K) >> 2; i += 256) {
        int off = i << 2;
        int rr = off / K, cc = off % K;
        int row = row0 + rr;
        float4 v = {0.f, 0.f, 0.f, 0.f};
        if (row < M) v = *(const float4*)(A + (long)row * K + cc);
        *(float4*)(sA + rr * K + cc) = v;
    }
    __syncthreads();

    int cg = tid & 31, rg = tid >> 5;
    int c0 = cg * NCT, r0 = rg * 8;
    float acc[8][NCT];
#pragma unroll
    for (int i = 0; i < 8; i++)
#pragma unroll
        for (int j = 0; j < NCT; j++) acc[i][j] = 0.f;

    for (int k = 0; k < K; k += 4) {
        float a[8][4];
#pragma unroll
        for (int i = 0; i < 8; i++)
            *(float4*)(a[i]) = *(const float4*)(sA + (r0 + i) * K + k);
#pragma unroll
        for (int j = 0; j < 4; j++) {
            float b[NCT];
            if constexpr (NCT == 4)
                *(float4*)b = *(const float4*)(sB + (k + j) * NC + c0);
            else
                *(float2*)b = *(const float2*)(sB + (k + j) * NC + c0);
#pragma unroll
            for (int i = 0; i < 8; i++)
#pragma unroll
                for (int jj = 0; jj < NCT; jj++)
                    acc[i][jj] = fmaf(a[i][j], b[jj], acc[i][jj]);
        }
    }

#pragma unroll
    for (int i = 0; i < 8; i++) {
        int row = row0 + r0 + i;
        if (row >= M) continue;
        float v[NCT];
#pragma unroll
        for (int jj = 0; jj < NCT; jj++) {
            float t = acc[i][jj] + (bias ? bias[c0 + jj] : 0.f);
            v[jj] = relu ? fmaxf(t, 0.f) : t;
        }
        if constexpr (NCT == 4)
            *(float4*)(C + (long)row * NC + c0) = *(float4*)v;
        else
            *(float2*)(C + (long)row * NC + c0) = *(float2*)v;
    }
}

// ---------------- fused gather-GEMM-scatter per relation ----------------
// blockIdx.y = relation; block handles 64 edges: gathers x[src] rows to LDS,
// multiplies by W[r] (LDS), atomic-adds inv_cnt-scaled rows into out[dst].
template <int NC>
__global__ __launch_bounds__(256) void agg_kernel(const float* __restrict__ x,
                                                  const float* __restrict__ Wall,
                                                  const int* __restrict__ elist,
                                                  const int* __restrict__ eoff,
                                                  const int* __restrict__ src,
                                                  const int* __restrict__ dst,
                                                  const float* __restrict__ invc,
                                                  float* __restrict__ out) {
    constexpr int NCT = NC / 32;
    __shared__ float sW[128 * NC];
    __shared__ float sA[64 * 128];
    __shared__ int sSrc[64];
    __shared__ int sDst[64];
    __shared__ float sScale[64];

    int r = blockIdx.y;
    int base = eoff[r];
    int cnt = eoff[r + 1] - base;
    int e0 = blockIdx.x * 64;
    if (e0 >= cnt) return;
    int tid = threadIdx.x;

    const float* W = Wall + r * 128 * NC;
    for (int i = tid; i < (128 * NC) >> 2; i += 256)
        ((float4*)sW)[i] = ((const float4*)W)[i];

    if (tid < 64) {
        int idx = e0 + tid;
        if (idx < cnt) {
            int e = elist[base + idx];
            sSrc[tid] = src[e];
            int d = dst[e];
            sDst[tid] = d;
            sScale[tid] = invc[r * NNODES + d];
        } else {
            sSrc[tid] = 0;
            sDst[tid] = -1;
            sScale[tid] = 0.f;
        }
    }
    __syncthreads();

#pragma unroll
    for (int j = 0; j < 8; j++) {
        int i4 = tid + 256 * j;                  // 2048 float4 = 64x128 floats
        int row = i4 >> 5, col = (i4 & 31) << 2;
        *(float4*)(sA + row * HIDC + col) =
            *(const float4*)(x + (long)sSrc[row] * HIDC + col);
    }
    __syncthreads();

    int cg = tid & 31, rg = tid >> 5;
    int c0 = cg * NCT, r0 = rg * 8;
    float acc[8][NCT];
#pragma unroll
    for (int i = 0; i < 8; i++)
#pragma unroll
        for (int j = 0; j < NCT; j++) acc[i][j] = 0.f;

    for (int k = 0; k < 128; k += 4) {
        float a[8][4];
#pragma unroll
        for (int i = 0; i < 8; i++)
            *(float4*)(a[i]) = *(const float4*)(sA + (r0 + i) * 128 + k);
#pragma unroll
        for (int j = 0; j < 4; j++) {
            float b[NCT];
            if constexpr (NCT == 4)
                *(float4*)b = *(const float4*)(sW + (k + j) * NC + c0);
            else
                *(float2*)b = *(const float2*)(sW + (k + j) * NC + c0);
#pragma unroll
            for (int i = 0; i < 8; i++)
#pragma unroll
                for (int jj = 0; jj < NCT; jj++)
                    acc[i][jj] = fmaf(a[i][j], b[jj], acc[i][jj]);
        }
    }

#pragma unroll
    for (int i = 0; i < 8; i++) {
        int row = r0 + i;
        int d = sDst[row];
        if (d < 0) continue;
        float s = sScale[row];
#pragma unroll
        for (int jj = 0; jj < NCT; jj++)
            atomicAdd(out + (long)d * NC + c0 + jj, s * acc[i][jj]);
    }
}

// ---------------- launch ----------------

extern "C" void kernel_launch(void* const* d_in, const int* in_sizes, int n_in,
                              void* d_out, int out_size, void* d_ws, size_t ws_size,
                              hipStream_t stream) {
    const float* xa     = (const float*)d_in[0];
    const float* xp     = (const float*)d_in[1];
    const int*   src    = (const int*)d_in[2];
    const int*   dst    = (const int*)d_in[3];
    const int*   et     = (const int*)d_in[4];
    const float* Wpa    = (const float*)d_in[5];
    const float* bpa    = (const float*)d_in[6];
    const float* Wpb    = (const float*)d_in[7];
    const float* bpb    = (const float*)d_in[8];
    const float* basis0 = (const float*)d_in[9];
    const float* comp0  = (const float*)d_in[10];
    const float* basis1 = (const float*)d_in[11];
    const float* comp1  = (const float*)d_in[12];
    const float* root1  = (const float*)d_in[13];
    const float* basis2 = (const float*)d_in[14];
    const float* comp2  = (const float*)d_in[15];
    const float* root2  = (const float*)d_in[16];

    // d_out layout: final [N,64] | x_lat0 [N,128] | x_lat1 [N,128] | x_lat2 [N,128]
    float* out_final = (float*)d_out;
    float* x0 = out_final + (size_t)NNODES * OUTCH;
    float* x1 = x0 + (size_t)NNODES * HIDC;
    float* x2 = x1 + (size_t)NNODES * HIDC;

    // workspace: ~6.3 MB total
    float* W0   = (float*)d_ws;                   // 4*128*128
    float* W1   = W0 + RELS * HIDC * HIDC;        // 4*128*128
    float* W2   = W1 + RELS * HIDC * HIDC;        // 4*128*64
    float* invc = W2 + RELS * HIDC * OUTCH;       // 4*200000
    int* relcnt = (int*)(invc + RELS * NNODES);   // 4
    int* eoff   = relcnt + 4;                     // 5 (pad to 8)
    int* cursor = eoff + 8;                       // 4
    int* elist  = cursor + 4;                     // 600000

    dim3 b256(256);
    int egrid = (NEDGE + 255) / 256;

    // degree counts -> inv, relation compaction
    hipMemsetAsync(invc, 0, (size_t)RELS * NNODES * sizeof(float), stream);
    hipLaunchKernelGGL(count_kernel, dim3(egrid), b256, 0, stream, dst, et, invc);
    hipLaunchKernelGGL(relcount_kernel, dim3(4), b256, 0, stream, invc, relcnt);
    hipLaunchKernelGGL(prefix_kernel, dim3(1), dim3(64), 0, stream, relcnt, eoff, cursor);
    hipLaunchKernelGGL(inv_kernel, dim3((RELS * NNODES + 255) / 256), b256, 0, stream, invc);
    hipLaunchKernelGGL(build_kernel, dim3(egrid), b256, 0, stream, et, eoff, cursor, elist);

    // materialize relation weights
    hipLaunchKernelGGL(makew_kernel, dim3((RELS * HIDC * HIDC + 255) / 256), b256, 0, stream,
                       basis0, comp0, W0, HIDC * HIDC);
    hipLaunchKernelGGL(makew_kernel, dim3((RELS * HIDC * HIDC + 255) / 256), b256, 0, stream,
                       basis1, comp1, W1, HIDC * HIDC);
    hipLaunchKernelGGL(makew_kernel, dim3((RELS * HIDC * OUTCH + 255) / 256), b256, 0, stream,
                       basis2, comp2, W2, HIDC * OUTCH);

    // projections -> x_lat0
    hipLaunchKernelGGL(gemm_kernel<128>, dim3((NAUT + 63) / 64), b256, 0, stream,
                       xa, Wpa, bpa, x0, NAUT, 64, 1);
    hipLaunchKernelGGL(gemm_kernel<128>, dim3((NAUT + 63) / 64), b256, 0, stream,
                       xp, Wpb, bpb, x0 + (size_t)NAUT * HIDC, NAUT, 96, 1);

    int agrid = (NEDGE + 63) / 64;  // upper bound; blocks beyond relation count exit early

    // conv0 (no root): x1 = relu(aggr(x0))
    hipMemsetAsync(x1, 0, (size_t)NNODES * HIDC * sizeof(float), stream);
    hipLaunchKernelGGL(agg_kernel<128>, dim3(agrid, RELS), b256, 0, stream,
                       x0, W0, elist, eoff, src, dst, invc, x1);
    hipLaunchKernelGGL(relu_kernel, dim3((NNODES * HIDC + 255) / 256), b256, 0, stream,
                       x1, NNODES * HIDC);

    // conv1 (root): x2 = relu(x1 @ root1 + aggr(x1))
    hipLaunchKernelGGL(gemm_kernel<128>, dim3((NNODES + 63) / 64), b256, 0, stream,
                       x1, root1, (const float*)nullptr, x2, NNODES, 128, 0);
    hipLaunchKernelGGL(agg_kernel<128>, dim3(agrid, RELS), b256, 0, stream,
                       x1, W1, elist, eoff, src, dst, invc, x2);
    hipLaunchKernelGGL(relu_kernel, dim3((NNODES * HIDC + 255) / 256), b256, 0, stream,
                       x2, NNODES * HIDC);

    // conv2 (root, no relu): final = x2 @ root2 + aggr(x2)
    hipLaunchKernelGGL(gemm_kernel<64>, dim3((NNODES + 63) / 64), b256, 0, stream,
                       x2, root2, (const float*)nullptr, out_final, NNODES, 128, 0);
    hipLaunchKernelGGL(agg_kernel<64>, dim3(agrid, RELS), b256, 0, stream,
                       x2, W2, elist, eoff, src, dst, invc, out_final);
}

// Round 2
// 3259.174 us; speedup vs baseline: 1.2749x; 1.2749x over previous
//
#include <hip/hip_runtime.h>

// Problem constants (fixed by reference).
constexpr int NNODES = 200000;
constexpr int NAUT   = 100000;
constexpr int NEDGE  = 600000;
constexpr int HIDC   = 128;
constexpr int OUTCH  = 64;
constexpr int RELS   = 4;
constexpr int SCAN_N = RELS * NNODES;  // 800000 bins

// ---------------- prep kernels ----------------

// W[r][i][o] = sum_b comp[r][b] * basis[b][i][o]
__global__ void makew_kernel(const float* __restrict__ basis, const float* __restrict__ comp,
                             float* __restrict__ W, int io_sz) {
    int idx = blockIdx.x * 256 + threadIdx.x;
    if (idx >= RELS * io_sz) return;
    int r = idx / io_sz, io = idx % io_sz;
    float s = 0.f;
#pragma unroll
    for (int b = 0; b < 4; b++) s += comp[r * 4 + b] * basis[b * io_sz + io];
    W[idx] = s;
}

// int count per (relation, dst) bin
__global__ void count_kernel(const int* __restrict__ dst, const int* __restrict__ et,
                             int* __restrict__ binCnt) {
    int e = blockIdx.x * 256 + threadIdx.x;
    if (e < NEDGE) atomicAdd(&binCnt[et[e] * NNODES + dst[e]], 1);
}

// ---- 3-phase exclusive scan over 800k bins (1024 elems/block) ----
__global__ void scan1_kernel(const int* __restrict__ binCnt, int* __restrict__ binOff,
                             int* __restrict__ blockSums) {
    __shared__ int s[256];
    int b = blockIdx.x, t = threadIdx.x;
    int base = b * 1024 + t * 4;
    int v[4], sum = 0;
#pragma unroll
    for (int i = 0; i < 4; i++) {
        v[i] = (base + i < SCAN_N) ? binCnt[base + i] : 0;
        sum += v[i];
    }
    s[t] = sum;
    __syncthreads();
    for (int off = 1; off < 256; off <<= 1) {
        int x = (t >= off) ? s[t - off] : 0;
        __syncthreads();
        if (t >= off) s[t] += x;
        __syncthreads();
    }
    int run = s[t] - sum;  // exclusive prefix of this thread's chunk
    if (t == 255) blockSums[b] = s[255];
#pragma unroll
    for (int i = 0; i < 4; i++) {
        if (base + i < SCAN_N) binOff[base + i] = run;
        run += v[i];
    }
}

__global__ void scan2_kernel(int* __restrict__ blockSums, int nb) {
    __shared__ int s[256];
    int t = threadIdx.x;
    int carry = 0;
    for (int base = 0; base < nb; base += 256) {
        int v = (base + t < nb) ? blockSums[base + t] : 0;
        s[t] = v;
        __syncthreads();
        for (int off = 1; off < 256; off <<= 1) {
            int x = (t >= off) ? s[t - off] : 0;
            __syncthreads();
            if (t >= off) s[t] += x;
            __syncthreads();
        }
        if (base + t < nb) blockSums[base + t] = carry + (s[t] - v);
        int total = s[255];
        __syncthreads();
        carry += total;
    }
}

__global__ void scan3_kernel(int* __restrict__ binOff, const int* __restrict__ blockSums) {
    int i = blockIdx.x * 256 + threadIdx.x;
    if (i < SCAN_N) binOff[i] += blockSums[i >> 10];
}

__global__ void eoff_kernel(const int* __restrict__ binOff, int* __restrict__ eoff) {
    int t = threadIdx.x;
    if (t < RELS) eoff[t] = binOff[t * NNODES];
    if (t == RELS) eoff[RELS] = NEDGE;
}

// binCnt reinterpreted in-place as float inv-count
__global__ void inv_kernel(int* __restrict__ binCnt) {
    int i = blockIdx.x * 256 + threadIdx.x;
    if (i < SCAN_N) {
        float c = (float)binCnt[i];
        ((float*)binCnt)[i] = 1.0f / fmaxf(c, 1.0f);
    }
}

// scatter edges into (relation, dst)-sorted order; mutates binOff into end-offsets
__global__ void scatter_kernel(const int* __restrict__ dst, const int* __restrict__ et,
                               int* __restrict__ binOff, int* __restrict__ elist) {
    int e = blockIdx.x * 256 + threadIdx.x;
    if (e < NEDGE) {
        int bin = et[e] * NNODES + dst[e];
        int pos = atomicAdd(&binOff[bin], 1);
        elist[pos] = e;
    }
}

__global__ void relu_kernel(float* __restrict__ p, int n) {
    int i = blockIdx.x * 256 + threadIdx.x;
    if (i < n) p[i] = fmaxf(p[i], 0.f);
}

// ---------------- GEMM: C[M,NC] = act(A[M,K] @ B[K,NC] + bias) ----------------
// 256 threads, tile 64 rows x NC cols, 8 rows x (NC/32) cols per thread.
// B read from global (L2-resident, <=64 KB); only A staged in LDS -> 3 blocks/CU.
template <int NC>
__global__ __launch_bounds__(256) void gemm_kernel(const float* __restrict__ A,
                                                   const float* __restrict__ B,
                                                   const float* __restrict__ bias,
                                                   float* __restrict__ C, int M, int K,
                                                   int relu) {
    constexpr int NCT = NC / 32;
    __shared__ float sA[64 * 128];
    int tid = threadIdx.x;
    int row0 = blockIdx.x * 64;

    for (int i = tid; i < (64 * K) >> 2; i += 256) {
        int off = i << 2;
        int rr = off / K, cc = off % K;
        int row = row0 + rr;
        float4 v = {0.f, 0.f, 0.f, 0.f};
        if (row < M) v = *(const float4*)(A + (long)row * K + cc);
        *(float4*)(sA + rr * K + cc) = v;
    }
    __syncthreads();

    int cg = tid & 31, rg = tid >> 5;
    int c0 = cg * NCT, r0 = rg * 8;
    float acc[8][NCT];
#pragma unroll
    for (int i = 0; i < 8; i++)
#pragma unroll
        for (int j = 0; j < NCT; j++) acc[i][j] = 0.f;

#pragma unroll 2
    for (int k = 0; k < K; k += 4) {
        float a[8][4];
#pragma unroll
        for (int i = 0; i < 8; i++)
            *(float4*)(a[i]) = *(const float4*)(sA + (r0 + i) * K + k);
#pragma unroll
        for (int j = 0; j < 4; j++) {
            float b[NCT];
            if constexpr (NCT == 4)
                *(float4*)b = *(const float4*)(B + (k + j) * NC + c0);
            else
                *(float2*)b = *(const float2*)(B + (k + j) * NC + c0);
#pragma unroll
            for (int i = 0; i < 8; i++)
#pragma unroll
                for (int jj = 0; jj < NCT; jj++)
                    acc[i][jj] = fmaf(a[i][j], b[jj], acc[i][jj]);
        }
    }

#pragma unroll
    for (int i = 0; i < 8; i++) {
        int row = row0 + r0 + i;
        if (row >= M) continue;
        float v[NCT];
#pragma unroll
        for (int jj = 0; jj < NCT; jj++) {
            float t = acc[i][jj] + (bias ? bias[c0 + jj] : 0.f);
            v[jj] = relu ? fmaxf(t, 0.f) : t;
        }
        if constexpr (NCT == 4)
            *(float4*)(C + (long)row * NC + c0) = *(float4*)v;
        else
            *(float2*)(C + (long)row * NC + c0) = *(float2*)v;
    }
}

// ---------------- fused gather-GEMM-scatter per relation ----------------
// blockIdx.y = relation; block handles 64 (dst-sorted) edges: gathers x[src]
// rows to LDS, multiplies by W[r] (global/L2), atomic-adds scaled rows to
// out[dst]. W NOT staged in LDS: LDS 33 KB -> ~3 blocks/CU vs 1 before.
template <int NC>
__global__ __launch_bounds__(256) void agg_kernel(const float* __restrict__ x,
                                                  const float* __restrict__ Wall,
                                                  const int* __restrict__ elist,
                                                  const int* __restrict__ eoff,
                                                  const int* __restrict__ src,
                                                  const int* __restrict__ dst,
                                                  const float* __restrict__ invc,
                                                  float* __restrict__ out) {
    constexpr int NCT = NC / 32;
    __shared__ float sA[64 * 128];
    __shared__ int sSrc[64];
    __shared__ int sDst[64];
    __shared__ float sScale[64];

    int r = blockIdx.y;
    int base = eoff[r];
    int cnt = eoff[r + 1] - base;
    int e0 = blockIdx.x * 64;
    if (e0 >= cnt) return;
    int tid = threadIdx.x;

    const float* __restrict__ W = Wall + r * 128 * NC;

    if (tid < 64) {
        int idx = e0 + tid;
        if (idx < cnt) {
            int e = elist[base + idx];
            sSrc[tid] = src[e];
            int d = dst[e];
            sDst[tid] = d;
            sScale[tid] = invc[r * NNODES + d];
        } else {
            sSrc[tid] = 0;
            sDst[tid] = -1;
            sScale[tid] = 0.f;
        }
    }
    __syncthreads();

#pragma unroll
    for (int j = 0; j < 8; j++) {
        int i4 = tid + 256 * j;  // 2048 float4 = 64x128 floats
        int row = i4 >> 5, col = (i4 & 31) << 2;
        *(float4*)(sA + row * HIDC + col) =
            *(const float4*)(x + (long)sSrc[row] * HIDC + col);
    }
    __syncthreads();

    int cg = tid & 31, rg = tid >> 5;
    int c0 = cg * NCT, r0 = rg * 8;
    float acc[8][NCT];
#pragma unroll
    for (int i = 0; i < 8; i++)
#pragma unroll
        for (int j = 0; j < NCT; j++) acc[i][j] = 0.f;

#pragma unroll 2
    for (int k = 0; k < 128; k += 4) {
        float a[8][4];
#pragma unroll
        for (int i = 0; i < 8; i++)
            *(float4*)(a[i]) = *(const float4*)(sA + (r0 + i) * 128 + k);
#pragma unroll
        for (int j = 0; j < 4; j++) {
            float b[NCT];
            if constexpr (NCT == 4)
                *(float4*)b = *(const float4*)(W + (k + j) * NC + c0);
            else
                *(float2*)b = *(const float2*)(W + (k + j) * NC + c0);
#pragma unroll
            for (int i = 0; i < 8; i++)
#pragma unroll
                for (int jj = 0; jj < NCT; jj++)
                    acc[i][jj] = fmaf(a[i][j], b[jj], acc[i][jj]);
        }
    }

#pragma unroll
    for (int i = 0; i < 8; i++) {
        int row = r0 + i;
        int d = sDst[row];
        if (d < 0) continue;
        float s = sScale[row];
#pragma unroll
        for (int jj = 0; jj < NCT; jj++)
            atomicAdd(out + (long)d * NC + c0 + jj, s * acc[i][jj]);
    }
}

// ---------------- launch ----------------

extern "C" void kernel_launch(void* const* d_in, const int* in_sizes, int n_in,
                              void* d_out, int out_size, void* d_ws, size_t ws_size,
                              hipStream_t stream) {
    const float* xa     = (const float*)d_in[0];
    const float* xp     = (const float*)d_in[1];
    const int*   src    = (const int*)d_in[2];
    const int*   dst    = (const int*)d_in[3];
    const int*   et     = (const int*)d_in[4];
    const float* Wpa    = (const float*)d_in[5];
    const float* bpa    = (const float*)d_in[6];
    const float* Wpb    = (const float*)d_in[7];
    const float* bpb    = (const float*)d_in[8];
    const float* basis0 = (const float*)d_in[9];
    const float* comp0  = (const float*)d_in[10];
    const float* basis1 = (const float*)d_in[11];
    const float* comp1  = (const float*)d_in[12];
    const float* root1  = (const float*)d_in[13];
    const float* basis2 = (const float*)d_in[14];
    const float* comp2  = (const float*)d_in[15];
    const float* root2  = (const float*)d_in[16];

    // d_out layout: final [N,64] | x_lat0 [N,128] | x_lat1 [N,128] | x_lat2 [N,128]
    float* out_final = (float*)d_out;
    float* x0 = out_final + (size_t)NNODES * OUTCH;
    float* x1 = x0 + (size_t)NNODES * HIDC;
    float* x2 = x1 + (size_t)NNODES * HIDC;

    // workspace (~9.5 MB)
    float* W0      = (float*)d_ws;                    // 4*128*128
    float* W1      = W0 + RELS * HIDC * HIDC;         // 4*128*128
    float* W2      = W1 + RELS * HIDC * HIDC;         // 4*128*64
    int* binCnt    = (int*)(W2 + RELS * HIDC * OUTCH);// 800000 (-> invc float in-place)
    int* binOff    = binCnt + SCAN_N;                 // 800000
    int* blockSums = binOff + SCAN_N;                 // 800
    int* eoff      = blockSums + 800;                 // 8
    int* elist     = eoff + 8;                        // 600000
    const float* invc = (const float*)binCnt;

    dim3 b256(256);
    int egrid = (NEDGE + 255) / 256;
    int nScanBlocks = (SCAN_N + 1023) / 1024;  // 782

    // ---- degree counts -> inv; counting-sort edges by (relation, dst) ----
    hipMemsetAsync(binCnt, 0, (size_t)SCAN_N * sizeof(int), stream);
    hipLaunchKernelGGL(count_kernel, dim3(egrid), b256, 0, stream, dst, et, binCnt);
    hipLaunchKernelGGL(scan1_kernel, dim3(nScanBlocks), b256, 0, stream, binCnt, binOff, blockSums);
    hipLaunchKernelGGL(scan2_kernel, dim3(1), b256, 0, stream, blockSums, nScanBlocks);
    hipLaunchKernelGGL(scan3_kernel, dim3((SCAN_N + 255) / 256), b256, 0, stream, binOff, blockSums);
    hipLaunchKernelGGL(eoff_kernel, dim3(1), dim3(64), 0, stream, binOff, eoff);
    hipLaunchKernelGGL(inv_kernel, dim3((SCAN_N + 255) / 256), b256, 0, stream, binCnt);
    hipLaunchKernelGGL(scatter_kernel, dim3(egrid), b256, 0, stream, dst, et, binOff, elist);

    // ---- materialize relation weights ----
    hipLaunchKernelGGL(makew_kernel, dim3((RELS * HIDC * HIDC + 255) / 256), b256, 0, stream,
                       basis0, comp0, W0, HIDC * HIDC);
    hipLaunchKernelGGL(makew_kernel, dim3((RELS * HIDC * HIDC + 255) / 256), b256, 0, stream,
                       basis1, comp1, W1, HIDC * HIDC);
    hipLaunchKernelGGL(makew_kernel, dim3((RELS * HIDC * OUTCH + 255) / 256), b256, 0, stream,
                       basis2, comp2, W2, HIDC * OUTCH);

    // ---- projections -> x_lat0 ----
    hipLaunchKernelGGL(gemm_kernel<128>, dim3((NAUT + 63) / 64), b256, 0, stream,
                       xa, Wpa, bpa, x0, NAUT, 64, 1);
    hipLaunchKernelGGL(gemm_kernel<128>, dim3((NAUT + 63) / 64), b256, 0, stream,
                       xp, Wpb, bpb, x0 + (size_t)NAUT * HIDC, NAUT, 96, 1);

    int agrid = (NEDGE + 63) / 64;  // upper bound; excess blocks exit early

    // conv0 (no root): x1 = relu(aggr(x0))
    hipMemsetAsync(x1, 0, (size_t)NNODES * HIDC * sizeof(float), stream);
    hipLaunchKernelGGL(agg_kernel<128>, dim3(agrid, RELS), b256, 0, stream,
                       x0, W0, elist, eoff, src, dst, invc, x1);
    hipLaunchKernelGGL(relu_kernel, dim3((NNODES * HIDC + 255) / 256), b256, 0, stream,
                       x1, NNODES * HIDC);

    // conv1 (root): x2 = relu(x1 @ root1 + aggr(x1))
    hipLaunchKernelGGL(gemm_kernel<128>, dim3((NNODES + 63) / 64), b256, 0, stream,
                       x1, root1, (const float*)nullptr, x2, NNODES, 128, 0);
    hipLaunchKernelGGL(agg_kernel<128>, dim3(agrid, RELS), b256, 0, stream,
                       x1, W1, elist, eoff, src, dst, invc, x2);
    hipLaunchKernelGGL(relu_kernel, dim3((NNODES * HIDC + 255) / 256), b256, 0, stream,
                       x2, NNODES * HIDC);

    // conv2 (root, no relu): final = x2 @ root2 + aggr(x2)
    hipLaunchKernelGGL(gemm_kernel<64>, dim3((NNODES + 63) / 64), b256, 0, stream,
                       x2, root2, (const float*)nullptr, out_final, NNODES, 128, 0);
    hipLaunchKernelGGL(agg_kernel<64>, dim3(agrid, RELS), b256, 0, stream,
                       x2, W2, elist, eoff, src, dst, invc, out_final);
}

// Round 3
// 1863.036 us; speedup vs baseline: 2.2303x; 1.7494x over previous
//
#include <hip/hip_runtime.h>

// Problem constants (fixed by reference).
constexpr int NNODES = 200000;
constexpr int NAUT   = 100000;
constexpr int NEDGE  = 600000;
constexpr int HIDC   = 128;
constexpr int OUTCH  = 64;
constexpr int RELS   = 4;
constexpr int SCAN_N = RELS * NNODES;  // 800000 bins
constexpr int LDA    = HIDC + 4;       // LDS pad: breaks row-aligned bank conflicts

// ---------------- prep kernels ----------------

// W[r][i][o] = sum_b comp[r][b] * basis[b][i][o]
__global__ void makew_kernel(const float* __restrict__ basis, const float* __restrict__ comp,
                             float* __restrict__ W, int io_sz) {
    int idx = blockIdx.x * 256 + threadIdx.x;
    if (idx >= RELS * io_sz) return;
    int r = idx / io_sz, io = idx % io_sz;
    float s = 0.f;
#pragma unroll
    for (int b = 0; b < 4; b++) s += comp[r * 4 + b] * basis[b * io_sz + io];
    W[idx] = s;
}

// int count per (relation, dst) bin
__global__ void count_kernel(const int* __restrict__ dst, const int* __restrict__ et,
                             int* __restrict__ bins) {
    int e = blockIdx.x * 256 + threadIdx.x;
    if (e < NEDGE) atomicAdd(&bins[et[e] * NNODES + dst[e]], 1);
}

// ---- 3-phase exclusive scan over 800k bins, in-place (counts -> starts) ----
__global__ void scan1_kernel(int* __restrict__ bins, int* __restrict__ blockSums) {
    __shared__ int s[256];
    int b = blockIdx.x, t = threadIdx.x;
    int base = b * 1024 + t * 4;
    int v[4], sum = 0;
#pragma unroll
    for (int i = 0; i < 4; i++) {
        v[i] = (base + i < SCAN_N) ? bins[base + i] : 0;
        sum += v[i];
    }
    s[t] = sum;
    __syncthreads();
    for (int off = 1; off < 256; off <<= 1) {
        int x = (t >= off) ? s[t - off] : 0;
        __syncthreads();
        if (t >= off) s[t] += x;
        __syncthreads();
    }
    int run = s[t] - sum;  // exclusive prefix of this thread's chunk
    if (t == 255) blockSums[b] = s[255];
#pragma unroll
    for (int i = 0; i < 4; i++) {
        if (base + i < SCAN_N) bins[base + i] = run;
        run += v[i];
    }
}

__global__ void scan2_kernel(int* __restrict__ blockSums, int nb) {
    __shared__ int s[256];
    int t = threadIdx.x;
    int carry = 0;
    for (int base = 0; base < nb; base += 256) {
        int v = (base + t < nb) ? blockSums[base + t] : 0;
        s[t] = v;
        __syncthreads();
        for (int off = 1; off < 256; off <<= 1) {
            int x = (t >= off) ? s[t - off] : 0;
            __syncthreads();
            if (t >= off) s[t] += x;
            __syncthreads();
        }
        if (base + t < nb) blockSums[base + t] = carry + (s[t] - v);
        int total = s[255];
        __syncthreads();
        carry += total;
    }
}

// add block carries; also produce the scatter-cursor copy
__global__ void scan3_kernel(int* __restrict__ bins, const int* __restrict__ blockSums,
                             int* __restrict__ binCur) {
    int i = blockIdx.x * 256 + threadIdx.x;
    if (i < SCAN_N) {
        int v = bins[i] + blockSums[i >> 10];
        bins[i] = v;
        binCur[i] = v;
    }
}

// scatter SRC ids into (relation,dst)-sorted order; binCur becomes end-offsets
__global__ void scatter_kernel(const int* __restrict__ src, const int* __restrict__ dst,
                               const int* __restrict__ et, int* __restrict__ binCur,
                               int* __restrict__ srcSorted) {
    int e = blockIdx.x * 256 + threadIdx.x;
    if (e < NEDGE) {
        int bin = et[e] * NNODES + dst[e];
        int pos = atomicAdd(&binCur[bin], 1);
        srcSorted[pos] = src[e];
    }
}

// ---------------- projection GEMM: C[M,128] = relu(A[M,K] @ B[K,128] + bias) ----
__global__ __launch_bounds__(256) void gemm_kernel(const float* __restrict__ A,
                                                   const float* __restrict__ B,
                                                   const float* __restrict__ bias,
                                                   float* __restrict__ C, int M, int K) {
    __shared__ float sA[64 * 128];
    int tid = threadIdx.x;
    int row0 = blockIdx.x * 64;

    for (int i = tid; i < (64 * K) >> 2; i += 256) {
        int off = i << 2;
        int rr = off / K, cc = off % K;
        int row = row0 + rr;
        float4 v = {0.f, 0.f, 0.f, 0.f};
        if (row < M) v = *(const float4*)(A + (long)row * K + cc);
        *(float4*)(sA + rr * K + cc) = v;
    }
    __syncthreads();

    int cg = tid & 31, rg = tid >> 5;
    int c0 = cg * 4, r0 = rg * 8;
    float acc[8][4];
#pragma unroll
    for (int i = 0; i < 8; i++)
#pragma unroll
        for (int j = 0; j < 4; j++) acc[i][j] = 0.f;

#pragma unroll 2
    for (int k = 0; k < K; k += 4) {
        float a[8][4];
#pragma unroll
        for (int i = 0; i < 8; i++)
            *(float4*)(a[i]) = *(const float4*)(sA + (r0 + i) * K + k);
#pragma unroll
        for (int j = 0; j < 4; j++) {
            float b[4];
            *(float4*)b = *(const float4*)(B + (k + j) * 128 + c0);
#pragma unroll
            for (int i = 0; i < 8; i++)
#pragma unroll
                for (int jj = 0; jj < 4; jj++)
                    acc[i][jj] = fmaf(a[i][j], b[jj], acc[i][jj]);
        }
    }

#pragma unroll
    for (int i = 0; i < 8; i++) {
        int row = row0 + r0 + i;
        if (row >= M) continue;
        float v[4];
#pragma unroll
        for (int jj = 0; jj < 4; jj++) v[jj] = fmaxf(acc[i][jj] + bias[c0 + jj], 0.f);
        *(float4*)(C + (long)row * 128 + c0) = *(float4*)v;
    }
}

// ---------------- fused dst-centric RGCN conv (NO atomics) ----------------
// Block owns 64 dst rows. Per relation: 4 threads/row sum the row's (sorted,
// contiguous) neighbors into registers, scale by 1/deg, stage to LDS; then a
// register-blocked GEMM vs W[r] (L2-resident) accumulates into C. Optional
// root phase (A = x[dst] rows, coalesced) and fused ReLU. Output written once.
template <int NC, bool HASROOT, bool DORELU>
__global__ __launch_bounds__(256) void conv_kernel(const float* __restrict__ x,
                                                   const float* __restrict__ Wall,
                                                   const float* __restrict__ root,
                                                   const int* __restrict__ binStart,
                                                   const int* __restrict__ binEnd,
                                                   const int* __restrict__ srcSorted,
                                                   float* __restrict__ out) {
    constexpr int NCT = NC / 32;
    __shared__ float sA[64 * LDA];
    int tid = threadIdx.x;
    int v0 = blockIdx.x * 64;

    int grow = tid >> 2;  // gather: 4 threads per row
    int gq = tid & 3;     // this thread's interleaved column slice
    int cg = tid & 31, rg = tid >> 5;
    int c0 = cg * NCT, r0 = rg * 8;

    float acc[8][NCT];
#pragma unroll
    for (int i = 0; i < 8; i++)
#pragma unroll
        for (int j = 0; j < NCT; j++) acc[i][j] = 0.f;

    constexpr int NPHASE = HASROOT ? RELS + 1 : RELS;
#pragma unroll 1
    for (int ph = 0; ph < NPHASE; ph++) {
        if (ph > 0) __syncthreads();  // protect sA from previous phase's readers
        if (ph < RELS) {
            int bin = ph * NNODES + v0 + grow;
            int s = binStart[bin], e = binEnd[bin];
            float4 a4[8];
#pragma unroll
            for (int i = 0; i < 8; i++) a4[i] = make_float4(0.f, 0.f, 0.f, 0.f);
            for (int j = s; j < e; j++) {
                const float* xs = x + (long)srcSorted[j] * HIDC;
#pragma unroll
                for (int i = 0; i < 8; i++) {
                    float4 v = *(const float4*)(xs + (gq + i * 4) * 4);
                    a4[i].x += v.x; a4[i].y += v.y; a4[i].z += v.z; a4[i].w += v.w;
                }
            }
            float sc = 1.0f / (float)max(e - s, 1);
#pragma unroll
            for (int i = 0; i < 8; i++) {
                float4 w = a4[i];
                w.x *= sc; w.y *= sc; w.z *= sc; w.w *= sc;
                *(float4*)(sA + grow * LDA + (gq + i * 4) * 4) = w;
            }
        } else {
            // root phase: coalesced load of the block's own 64 x-rows
#pragma unroll
            for (int i = 0; i < 8; i++) {
                int i4 = tid + 256 * i;  // 2048 float4 = 64x128 floats
                int row = i4 >> 5, col4 = i4 & 31;
                *(float4*)(sA + row * LDA + col4 * 4) =
                    *(const float4*)(x + (long)(v0 + row) * HIDC + col4 * 4);
            }
        }
        __syncthreads();

        const float* __restrict__ B = (ph < RELS) ? (Wall + ph * HIDC * NC) : root;
#pragma unroll 2
        for (int k = 0; k < HIDC; k += 4) {
            float a[8][4];
#pragma unroll
            for (int i = 0; i < 8; i++)
                *(float4*)(a[i]) = *(const float4*)(sA + (r0 + i) * LDA + k);
#pragma unroll
            for (int j = 0; j < 4; j++) {
                float b[NCT];
                if constexpr (NCT == 4)
                    *(float4*)b = *(const float4*)(B + (k + j) * NC + c0);
                else
                    *(float2*)b = *(const float2*)(B + (k + j) * NC + c0);
#pragma unroll
                for (int i = 0; i < 8; i++)
#pragma unroll
                    for (int jj = 0; jj < NCT; jj++)
                        acc[i][jj] = fmaf(a[i][j], b[jj], acc[i][jj]);
            }
        }
    }

    // epilogue: exactly one coalesced store per output element
#pragma unroll
    for (int i = 0; i < 8; i++) {
        int row = v0 + r0 + i;  // NNODES % 64 == 0: no guard needed
        float v[NCT];
#pragma unroll
        for (int jj = 0; jj < NCT; jj++)
            v[jj] = DORELU ? fmaxf(acc[i][jj], 0.f) : acc[i][jj];
        if constexpr (NCT == 4)
            *(float4*)(out + (long)row * NC + c0) = *(float4*)v;
        else
            *(float2*)(out + (long)row * NC + c0) = *(float2*)v;
    }
}

// ---------------- launch ----------------

extern "C" void kernel_launch(void* const* d_in, const int* in_sizes, int n_in,
                              void* d_out, int out_size, void* d_ws, size_t ws_size,
                              hipStream_t stream) {
    const float* xa     = (const float*)d_in[0];
    const float* xp     = (const float*)d_in[1];
    const int*   src    = (const int*)d_in[2];
    const int*   dst    = (const int*)d_in[3];
    const int*   et     = (const int*)d_in[4];
    const float* Wpa    = (const float*)d_in[5];
    const float* bpa    = (const float*)d_in[6];
    const float* Wpb    = (const float*)d_in[7];
    const float* bpb    = (const float*)d_in[8];
    const float* basis0 = (const float*)d_in[9];
    const float* comp0  = (const float*)d_in[10];
    const float* basis1 = (const float*)d_in[11];
    const float* comp1  = (const float*)d_in[12];
    const float* root1  = (const float*)d_in[13];
    const float* basis2 = (const float*)d_in[14];
    const float* comp2  = (const float*)d_in[15];
    const float* root2  = (const float*)d_in[16];

    // d_out layout: final [N,64] | x_lat0 [N,128] | x_lat1 [N,128] | x_lat2 [N,128]
    float* out_final = (float*)d_out;
    float* x0 = out_final + (size_t)NNODES * OUTCH;
    float* x1 = x0 + (size_t)NNODES * HIDC;
    float* x2 = x1 + (size_t)NNODES * HIDC;

    // workspace (~9.3 MB)
    float* W0      = (float*)d_ws;                      // 4*128*128
    float* W1      = W0 + RELS * HIDC * HIDC;           // 4*128*128
    float* W2      = W1 + RELS * HIDC * HIDC;           // 4*128*64
    int* bins      = (int*)(W2 + RELS * HIDC * OUTCH);  // 800000: counts -> starts
    int* binCur    = bins + SCAN_N;                     // 800000: cursor -> ends
    int* blockSums = binCur + SCAN_N;                   // 800
    int* srcSorted = blockSums + 800;                   // 600000

    dim3 b256(256);
    int egrid = (NEDGE + 255) / 256;
    int nScanBlocks = (SCAN_N + 1023) / 1024;  // 782

    // ---- counting-sort of src ids by (relation, dst) ----
    hipMemsetAsync(bins, 0, (size_t)SCAN_N * sizeof(int), stream);
    hipLaunchKernelGGL(count_kernel, dim3(egrid), b256, 0, stream, dst, et, bins);
    hipLaunchKernelGGL(scan1_kernel, dim3(nScanBlocks), b256, 0, stream, bins, blockSums);
    hipLaunchKernelGGL(scan2_kernel, dim3(1), b256, 0, stream, blockSums, nScanBlocks);
    hipLaunchKernelGGL(scan3_kernel, dim3((SCAN_N + 255) / 256), b256, 0, stream,
                       bins, blockSums, binCur);
    hipLaunchKernelGGL(scatter_kernel, dim3(egrid), b256, 0, stream,
                       src, dst, et, binCur, srcSorted);

    // ---- materialize relation weights ----
    hipLaunchKernelGGL(makew_kernel, dim3((RELS * HIDC * HIDC + 255) / 256), b256, 0, stream,
                       basis0, comp0, W0, HIDC * HIDC);
    hipLaunchKernelGGL(makew_kernel, dim3((RELS * HIDC * HIDC + 255) / 256), b256, 0, stream,
                       basis1, comp1, W1, HIDC * HIDC);
    hipLaunchKernelGGL(makew_kernel, dim3((RELS * HIDC * OUTCH + 255) / 256), b256, 0, stream,
                       basis2, comp2, W2, HIDC * OUTCH);

    // ---- projections -> x_lat0 ----
    hipLaunchKernelGGL(gemm_kernel, dim3((NAUT + 63) / 64), b256, 0, stream,
                       xa, Wpa, bpa, x0, NAUT, 64);
    hipLaunchKernelGGL(gemm_kernel, dim3((NAUT + 63) / 64), b256, 0, stream,
                       xp, Wpb, bpb, x0 + (size_t)NAUT * HIDC, NAUT, 96);

    int cgrid = NNODES / 64;  // 3125, exact

    // conv0: x1 = relu(aggr(x0))            (no root)
    hipLaunchKernelGGL((conv_kernel<128, false, true>), dim3(cgrid), b256, 0, stream,
                       x0, W0, (const float*)nullptr, bins, binCur, srcSorted, x1);
    // conv1: x2 = relu(x1 @ root1 + aggr(x1))
    hipLaunchKernelGGL((conv_kernel<128, true, true>), dim3(cgrid), b256, 0, stream,
                       x1, W1, root1, bins, binCur, srcSorted, x2);
    // conv2: final = x2 @ root2 + aggr(x2)  (no relu)
    hipLaunchKernelGGL((conv_kernel<64, true, false>), dim3(cgrid), b256, 0, stream,
                       x2, W2, root2, bins, binCur, srcSorted, out_final);
}